// Round 11
// baseline (870.365 us; speedup 1.0000x reference)
//
#include <hip/hip_runtime.h>
#include <stdint.h>

#define NPTS   4096
#define NPOINT 1024
#define NSAMP  32
#define NROWS  262144   // B*NPOINT*NSAMP
#define RAD2   0.04f

typedef float v2f __attribute__((ext_vector_type(2)));
typedef __attribute__((ext_vector_type(8))) short bf16x8;
typedef __attribute__((ext_vector_type(4))) float f32x4;

// bf16 round-to-nearest-even
__device__ __forceinline__ unsigned short f2bf(float x) {
    unsigned u = __float_as_uint(x);
    return (unsigned short)((u + 0x7FFFu + ((u >> 16) & 1u)) >> 16);
}
__device__ __forceinline__ unsigned pack2bf(float a, float b) {
    return (unsigned)f2bf(a) | ((unsigned)f2bf(b) << 16);
}

// fused-DPP reduction helpers (single-use feeds -> v_max_f32_dpp / v_min_u32_dpp)
#define DPPMAX(v, C)                                                           \
    fmaxf(__int_as_float(__builtin_amdgcn_update_dpp(                          \
              0, __float_as_int(v), C, 0xf, 0xf, true)),                       \
          (v))
#define DPPMIN(v, C)                                                           \
    ({ unsigned _o = (unsigned)__builtin_amdgcn_update_dpp(                    \
           -1, (int)(v), C, 0xf, 0xf, false);                                  \
       (_o < (v)) ? _o : (v); })

// ---------------------------------------------------------------------------
// FPS: one block per batch, 512 threads (8 waves, 2 waves/SIMD for latency
// hiding of the DPP/LDS/barrier chains). Distance chain bit-exact vs fp32
// reference (packed fp32 IEEE-identical; contraction disabled).
// Reduce: fused v_max_f32_dpp chain -> readlane(63) -> bit-compare ->
// v_min_u32_dpp index chain -> lane63 writes (value, ~minidx) key -> ONE
// barrier -> all threads select max of 8 keys -> pxyz[farthest] LDS read.
// Selection provably identical to u64 lexicographic reduce (R4-R10).
// ---------------------------------------------------------------------------
__global__ __launch_bounds__(512) void fps_kernel(const float* __restrict__ xyz,
                                                  float* __restrict__ outx)
{
    __shared__ __align__(16) float4 pxyz[NPTS];
    __shared__ __align__(16) float4 orec[NPOINT];
    __shared__ __align__(16) unsigned long long wkey[2][8];
    const int b = blockIdx.x, tid = threadIdx.x;
    const int lane = tid & 63, wid = tid >> 6;
    const float* base = xyz + b * 3 * NPTS;

    float Xs[8], Ys[8], Zs[8];
#pragma unroll
    for (int j = 0; j < 8; ++j) {
        const int n = j * 512 + tid;
        Xs[j] = base[n];
        Ys[j] = base[NPTS + n];
        Zs[j] = base[2 * NPTS + n];
        pxyz[n] = make_float4(Xs[j], Ys[j], Zs[j], 0.0f);
    }
    v2f X2[4], Y2[4], Z2[4], D2[4];
#pragma unroll
    for (int j = 0; j < 4; ++j) {
        X2[j] = (v2f){Xs[2 * j], Xs[2 * j + 1]};
        Y2[j] = (v2f){Ys[2 * j], Ys[2 * j + 1]};
        Z2[j] = (v2f){Zs[2 * j], Zs[2 * j + 1]};
        D2[j] = (v2f){1e10f, 1e10f};
    }
    __syncthreads();
    float4 c4 = pxyz[0];
    float cx = c4.x, cy = c4.y, cz = c4.z;

    for (int t = 0; t < NPOINT; ++t) {
        if (tid == 0) orec[t] = make_float4(cx, cy, cz, 0.0f);
        const v2f cxv = (v2f){cx, cx}, cyv = (v2f){cy, cy}, czv = (v2f){cz, cz};
        float bv = -1.0f; int bi = 0;
#pragma unroll
        for (int j = 0; j < 4; ++j) {
            v2f nd;
            {
#pragma clang fp contract(off)
                const v2f dx = X2[j] - cxv;
                const v2f dy = Y2[j] - cyv;
                const v2f dz = Z2[j] - czv;
                const v2f m0 = dx * dx;
                const v2f m1 = dy * dy;
                const v2f m2 = dz * dz;
                const v2f d = (m0 + m1) + m2;
                nd = __builtin_elementwise_min(D2[j], d);
            }
            D2[j] = nd;
            // indices ascend with j within a thread -> strict > keeps smallest
            if (nd.x > bv) { bv = nd.x; bi = j * 1024 + tid; }
            if (nd.y > bv) { bv = nd.y; bi = j * 1024 + 512 + tid; }
        }
        // value-first fused-DPP argmax (identical selection to u64 key reduce)
        float rv = bv;                       // bv >= 0 (bound_ctrl 0-fill safe)
        rv = DPPMAX(rv, 0x111);              // row_shr:1
        rv = DPPMAX(rv, 0x112);              // row_shr:2
        rv = DPPMAX(rv, 0x114);              // row_shr:4
        rv = DPPMAX(rv, 0x118);              // row_shr:8
        rv = DPPMAX(rv, 0x142);              // row_bcast:15
        rv = DPPMAX(rv, 0x143);              // row_bcast:31
        const unsigned wmax =
            (unsigned)__builtin_amdgcn_readlane(__float_as_int(rv), 63);
        unsigned cand = (__float_as_uint(bv) == wmax) ? (unsigned)bi
                                                      : 0xFFFFFFFFu;
        cand = DPPMIN(cand, 0x111);
        cand = DPPMIN(cand, 0x112);
        cand = DPPMIN(cand, 0x114);
        cand = DPPMIN(cand, 0x118);
        cand = DPPMIN(cand, 0x142);
        cand = DPPMIN(cand, 0x143);
        if (lane == 63)
            wkey[t & 1][wid] = ((unsigned long long)wmax << 32) |
                               (unsigned)(~cand);
        __syncthreads();
        const ulonglong2* wk = (const ulonglong2*)wkey[t & 1];
        const ulonglong2 ka = wk[0], kb = wk[1], kc = wk[2], kd = wk[3];
        unsigned long long k01 = ka.x > ka.y ? ka.x : ka.y;
        unsigned long long k23 = kb.x > kb.y ? kb.x : kb.y;
        unsigned long long k45 = kc.x > kc.y ? kc.x : kc.y;
        unsigned long long k67 = kd.x > kd.y ? kd.x : kd.y;
        unsigned long long k03 = k01 > k23 ? k01 : k23;
        unsigned long long k47 = k45 > k67 ? k45 : k67;
        const unsigned long long kk = k03 > k47 ? k03 : k47;
        const int farthest = (int)(~(unsigned)kk) & (NPTS - 1);
        c4 = pxyz[farthest];
        cx = c4.x; cy = c4.y; cz = c4.z;
    }
    __syncthreads();
    float* ox = outx + b * 3 * NPOINT;
    for (int i = tid; i < NPOINT; i += 512) {
        const float4 c = orec[i];
        ox[i]              = c.x;
        ox[NPOINT + i]     = c.y;
        ox[2 * NPOINT + i] = c.z;
    }
}

// ---------------------------------------------------------------------------
// Ball query + fused feature moments. One wave per query: first 32 in-radius
// indices (ascending); then lanes 0-31 gather their row's features and the
// block accumulates m1[6] / M2[36] (stats0 is bilinear in W0 -> bn0 derives
// from these 42 sums; computed inline in mlp kernels).
// ---------------------------------------------------------------------------
__global__ __launch_bounds__(256) void ball_kernel(const float* __restrict__ xyz,
                                                   const float* __restrict__ pts,
                                                   const float* __restrict__ outx,
                                                   int* __restrict__ idxbuf,
                                                   float* __restrict__ mom)
{
    __shared__ float red[4][42];
    const int tid = threadIdx.x;
    const int w = blockIdx.x * 4 + (tid >> 6);
    const int lane = tid & 63, wid = tid >> 6;
    const int b = w >> 10, s = w & 1023;
    const float* base = xyz + b * 3 * NPTS;
    const float cx = outx[b * 3 * NPOINT + s];
    const float cy = outx[b * 3 * NPOINT + NPOINT + s];
    const float cz = outx[b * 3 * NPOINT + 2 * NPOINT + s];
    const float sumS = __fadd_rn(__fadd_rn(__fmul_rn(cx, cx), __fmul_rn(cy, cy)),
                                 __fmul_rn(cz, cz));
    int cnt = 0, first_n = -1;
    int* myidx = idxbuf + w * NSAMP;

    for (int chunk = 0; chunk < NPTS / 64 && cnt < NSAMP; ++chunk) {
        const int n = chunk * 64 + lane;
        float nx = base[n], ny = base[NPTS + n], nz = base[2 * NPTS + n];
        float sumN = __fadd_rn(__fadd_rn(__fmul_rn(nx, nx), __fmul_rn(ny, ny)),
                               __fmul_rn(nz, nz));
        float dot = __fadd_rn(__fadd_rn(__fmul_rn(cx, nx), __fmul_rn(cy, ny)),
                              __fmul_rn(cz, nz));
        float sq = __fsub_rn(__fadd_rn(sumS, sumN), __fmul_rn(2.0f, dot));
        bool keep = (sq <= RAD2);
        unsigned long long mask = __ballot(keep);
        if (first_n < 0 && mask) first_n = chunk * 64 + (int)__builtin_ctzll(mask);
        int pos = cnt + __popcll(mask & ((1ull << lane) - 1ull));
        if (keep && pos < NSAMP) myidx[pos] = n;
        cnt += __popcll(mask);
    }
    if (cnt < NSAMP) {
        if (lane >= cnt && lane < NSAMP) myidx[lane] = first_n;
    }

    // ---- fused moments for this wave's 32 rows ----
    float m[42];
#pragma unroll
    for (int i = 0; i < 42; ++i) m[i] = 0.f;
    if (lane < 32) {
        const int idx = myidx[lane];
        const float* pb = pts + b * 3 * NPTS;
        float f[6];
        f[0] = base[idx] - cx;
        f[1] = base[NPTS + idx] - cy;
        f[2] = base[2 * NPTS + idx] - cz;
        f[3] = pb[idx];
        f[4] = pb[NPTS + idx];
        f[5] = pb[2 * NPTS + idx];
#pragma unroll
        for (int c = 0; c < 6; ++c) m[c] = f[c];
#pragma unroll
        for (int c = 0; c < 6; ++c)
#pragma unroll
            for (int d = 0; d < 6; ++d)
                m[6 + c * 6 + d] = f[c] * f[d];
    }
#pragma unroll
    for (int i = 0; i < 42; ++i) {
        float v = m[i];
        v += __shfl_xor(v, 1);  v += __shfl_xor(v, 2);  v += __shfl_xor(v, 4);
        v += __shfl_xor(v, 8);  v += __shfl_xor(v, 16); v += __shfl_xor(v, 32);
        m[i] = v;
    }
    if (lane == 0) {
#pragma unroll
        for (int i = 0; i < 42; ++i) red[wid][i] = m[i];
    }
    __syncthreads();
    if (tid < 42)
        atomicAdd(&mom[tid], red[0][tid] + red[1][tid] + red[2][tid] + red[3][tid]);
}

// ---------------------------------------------------------------------------
__device__ __forceinline__ void load_feats(const float* __restrict__ xyz,
                                           const float* __restrict__ pts,
                                           const float* __restrict__ outx,
                                           int r, int idx, float f[6])
{
    const int b = r >> 15;
    const int s = (r >> 5) & 1023;
    const float* xb = xyz + b * 3 * NPTS;
    const float* pb = pts + b * 3 * NPTS;
    const float* ob = outx + b * 3 * NPOINT;
    f[0] = xb[idx] - ob[s];
    f[1] = xb[NPTS + idx] - ob[NPOINT + s];
    f[2] = xb[2 * NPTS + idx] - ob[2 * NPOINT + s];
    f[3] = pb[idx];
    f[4] = pb[NPTS + idx];
    f[5] = pb[2 * NPTS + idx];
}

// bn0 from feature moments (biases cancel through BN shift; bilinear in W0)
__device__ __forceinline__ void compute_bn0(int o, const float* __restrict__ mom,
                                            const float* __restrict__ w0,
                                            const float* __restrict__ g,
                                            const float* __restrict__ be,
                                            float* __restrict__ sbn0)
{
    float w[6];
#pragma unroll
    for (int c = 0; c < 6; ++c) w[c] = w0[o * 6 + c];
    const float inv = 1.0f / (float)NROWS;
    float mean = 0.f;
#pragma unroll
    for (int c = 0; c < 6; ++c) mean = fmaf(w[c], mom[c], mean);
    mean *= inv;
    float ey2 = 0.f;
#pragma unroll
    for (int c = 0; c < 6; ++c) {
        float t = 0.f;
#pragma unroll
        for (int d = 0; d < 6; ++d) t = fmaf(w[d], mom[6 + c * 6 + d], t);
        ey2 = fmaf(w[c], t, ey2);
    }
    ey2 *= inv;
    const float var = ey2 - mean * mean;
    const float scale = g[o] * rsqrtf(var + 1e-5f);
    sbn0[o] = scale;
    sbn0[64 + o] = be[o] - mean * scale;
}

// ===========================================================================
// MFMA MLP kernels (R8-validated): 512 blocks x 512 rows (4 chunks of 128),
// weights staged once per block, stats in registers across chunks.
// mfma_f32_16x16x32_bf16: A[m=lane&15][k=q*8+j], B[k=q*8+j][n=lane&15],
// D[row=q*4+r][col=lane&15]  (q = lane>>4).
// ===========================================================================
#define XP  72
#define WP  72
#define W0P 40

// ---- mlp1: f -> L0 -> bn0(inline from moments) -> L1 -> stats1 --------------
__global__ __launch_bounds__(256, 2) void mlp1_kernel(
    const float* __restrict__ xyz, const float* __restrict__ pts,
    const float* __restrict__ outx, const int* __restrict__ idxbuf,
    const float* __restrict__ w0, const float* __restrict__ mom,
    const float* __restrict__ g0, const float* __restrict__ be0,
    const float* __restrict__ w1, float* __restrict__ stats)
{
    __shared__ __align__(16) unsigned short sw0[64 * W0P];
    __shared__ __align__(16) unsigned short sw1[64 * WP];
    __shared__ __align__(16) unsigned short xb[4][32 * XP];
    __shared__ float sbn0[128];
    __shared__ float red[4][128];
    const int tid = threadIdx.x, lane = tid & 63, wid = tid >> 6;

    for (int i = tid; i < 64 * W0P / 2; i += 256) ((unsigned*)sw0)[i] = 0;
    if (tid < 64) compute_bn0(tid, mom, w0, g0, be0, sbn0);
    __syncthreads();
    for (int i = tid; i < 192; i += 256) {
        const int o = i / 3, c = (i % 3) * 2;
        *(unsigned*)&sw0[o * W0P + c] = pack2bf(w0[o * 6 + c], w0[o * 6 + c + 1]);
    }
    for (int i = tid; i < 2048; i += 256) {
        const int o = i >> 5, k = (i & 31) * 2;
        *(unsigned*)&sw1[o * WP + k] = pack2bf(w1[o * 64 + k], w1[o * 64 + k + 1]);
    }

    const int mh = lane & 15, q = lane >> 4;
    unsigned short* X = xb[wid];
    const int rbase = blockIdx.x * 512 + wid * 32;
    float sA[4] = {0.f, 0.f, 0.f, 0.f}, qA[4] = {0.f, 0.f, 0.f, 0.f};

    for (int c = 0; c < 4; ++c) {
        __syncthreads();
        if (lane < 32) {
            const int r = rbase + c * 128 + lane;
            float f[6];
            load_feats(xyz, pts, outx, r, idxbuf[r], f);
            uint4* xq = (uint4*)&xb[wid][lane * XP];
            xq[0] = make_uint4(pack2bf(f[0], f[1]), pack2bf(f[2], f[3]),
                               pack2bf(f[4], f[5]), 0u);
            xq[1] = make_uint4(0u, 0u, 0u, 0u);
            xq[2] = make_uint4(0u, 0u, 0u, 0u);
            xq[3] = make_uint4(0u, 0u, 0u, 0u);
        }
        __syncthreads();
        // L0
        f32x4 acc0[2][4] = {};
        {
            bf16x8 a[2], bw[4];
#pragma unroll
            for (int mt = 0; mt < 2; ++mt)
                a[mt] = *(const bf16x8*)&X[(mt * 16 + mh) * XP + q * 8];
#pragma unroll
            for (int nt = 0; nt < 4; ++nt)
                bw[nt] = *(const bf16x8*)&sw0[(nt * 16 + mh) * W0P + q * 8];
#pragma unroll
            for (int mt = 0; mt < 2; ++mt)
#pragma unroll
                for (int nt = 0; nt < 4; ++nt)
                    acc0[mt][nt] = __builtin_amdgcn_mfma_f32_16x16x32_bf16(
                        a[mt], bw[nt], acc0[mt][nt], 0, 0, 0);
        }
        __syncthreads();
#pragma unroll
        for (int nt = 0; nt < 4; ++nt) {
            const int ch = nt * 16 + mh;
            const float sc = sbn0[ch], sh = sbn0[64 + ch];
#pragma unroll
            for (int mt = 0; mt < 2; ++mt)
#pragma unroll
                for (int rr = 0; rr < 4; ++rr) {
                    const float v = fmaxf(fmaf(acc0[mt][nt][rr], sc, sh), 0.0f);
                    X[(mt * 16 + q * 4 + rr) * XP + ch] = f2bf(v);
                }
        }
        __syncthreads();
        // L1
        f32x4 acc1[2][4] = {};
#pragma unroll
        for (int ks = 0; ks < 2; ++ks) {
            bf16x8 a[2], bw[4];
#pragma unroll
            for (int mt = 0; mt < 2; ++mt)
                a[mt] = *(const bf16x8*)&X[(mt * 16 + mh) * XP + ks * 32 + q * 8];
#pragma unroll
            for (int nt = 0; nt < 4; ++nt)
                bw[nt] = *(const bf16x8*)&sw1[(nt * 16 + mh) * WP + ks * 32 + q * 8];
#pragma unroll
            for (int mt = 0; mt < 2; ++mt)
#pragma unroll
                for (int nt = 0; nt < 4; ++nt)
                    acc1[mt][nt] = __builtin_amdgcn_mfma_f32_16x16x32_bf16(
                        a[mt], bw[nt], acc1[mt][nt], 0, 0, 0);
        }
#pragma unroll
        for (int nt = 0; nt < 4; ++nt)
#pragma unroll
            for (int mt = 0; mt < 2; ++mt)
#pragma unroll
                for (int rr = 0; rr < 4; ++rr) {
                    const float v = acc1[mt][nt][rr];
                    sA[nt] += v;
                    qA[nt] = fmaf(v, v, qA[nt]);
                }
    }
#pragma unroll
    for (int nt = 0; nt < 4; ++nt) {
        float s = sA[nt], qq = qA[nt];
        s += __shfl_xor(s, 16); qq += __shfl_xor(qq, 16);
        s += __shfl_xor(s, 32); qq += __shfl_xor(qq, 32);
        if (q == 0) {
            red[wid][nt * 16 + mh] = s;
            red[wid][64 + nt * 16 + mh] = qq;
        }
    }
    __syncthreads();
    if (tid < 128)
        atomicAdd(&stats[tid],
                  red[0][tid] + red[1][tid] + red[2][tid] + red[3][tid]);
}

// ---- mlp2: f -> L0 -> bn0 -> L1 -> bn1(inline) -> L2 -> stats2 + group max --
__global__ __launch_bounds__(256, 2) void mlp2_kernel(
    const float* __restrict__ xyz, const float* __restrict__ pts,
    const float* __restrict__ outx, const int* __restrict__ idxbuf,
    const float* __restrict__ w0, const float* __restrict__ mom,
    const float* __restrict__ g0, const float* __restrict__ be0,
    const float* __restrict__ w1, const float* __restrict__ stats1,
    const float* __restrict__ g1, const float* __restrict__ be1,
    const float* __restrict__ w2,
    float* __restrict__ stats, float* __restrict__ gmax)
{
    __shared__ __align__(16) unsigned short sw0[64 * W0P];
    __shared__ __align__(16) unsigned short sw1[64 * WP];
    __shared__ __align__(16) unsigned short sw2[128 * WP];
    __shared__ __align__(16) unsigned short xb[4][32 * XP];
    __shared__ float sbn0[128];
    __shared__ float sbn1[128];
    __shared__ float red[4][256];
    const int tid = threadIdx.x, lane = tid & 63, wid = tid >> 6;

    for (int i = tid; i < 64 * W0P / 2; i += 256) ((unsigned*)sw0)[i] = 0;
    if (tid < 64) {
        compute_bn0(tid, mom, w0, g0, be0, sbn0);
    } else if (tid < 128) {
        const int ch = tid - 64;
        const float inv = 1.0f / (float)NROWS;
        const float mean = stats1[ch] * inv;
        const float var = stats1[64 + ch] * inv - mean * mean;
        const float scale = g1[ch] * rsqrtf(var + 1e-5f);
        sbn1[ch] = scale;
        sbn1[64 + ch] = be1[ch] - mean * scale;
    }
    __syncthreads();
    for (int i = tid; i < 192; i += 256) {
        const int o = i / 3, c = (i % 3) * 2;
        *(unsigned*)&sw0[o * W0P + c] = pack2bf(w0[o * 6 + c], w0[o * 6 + c + 1]);
    }
    for (int i = tid; i < 2048; i += 256) {
        const int o = i >> 5, k = (i & 31) * 2;
        *(unsigned*)&sw1[o * WP + k] = pack2bf(w1[o * 64 + k], w1[o * 64 + k + 1]);
    }
    for (int i = tid; i < 4096; i += 256) {
        const int o = i >> 5, k = (i & 31) * 2;
        *(unsigned*)&sw2[o * WP + k] = pack2bf(w2[o * 64 + k], w2[o * 64 + k + 1]);
    }

    const int mh = lane & 15, q = lane >> 4;
    unsigned short* X = xb[wid];
    const int rbase = blockIdx.x * 512 + wid * 32;
    float sA[8], qA[8];
#pragma unroll
    for (int i = 0; i < 8; ++i) { sA[i] = 0.f; qA[i] = 0.f; }

    for (int c = 0; c < 4; ++c) {
        __syncthreads();
        if (lane < 32) {
            const int r = rbase + c * 128 + lane;
            float f[6];
            load_feats(xyz, pts, outx, r, idxbuf[r], f);
            uint4* xq = (uint4*)&xb[wid][lane * XP];
            xq[0] = make_uint4(pack2bf(f[0], f[1]), pack2bf(f[2], f[3]),
                               pack2bf(f[4], f[5]), 0u);
            xq[1] = make_uint4(0u, 0u, 0u, 0u);
            xq[2] = make_uint4(0u, 0u, 0u, 0u);
            xq[3] = make_uint4(0u, 0u, 0u, 0u);
        }
        __syncthreads();
        // L0
        f32x4 acc0[2][4] = {};
        {
            bf16x8 a[2], bw[4];
#pragma unroll
            for (int mt = 0; mt < 2; ++mt)
                a[mt] = *(const bf16x8*)&X[(mt * 16 + mh) * XP + q * 8];
#pragma unroll
            for (int nt = 0; nt < 4; ++nt)
                bw[nt] = *(const bf16x8*)&sw0[(nt * 16 + mh) * W0P + q * 8];
#pragma unroll
            for (int mt = 0; mt < 2; ++mt)
#pragma unroll
                for (int nt = 0; nt < 4; ++nt)
                    acc0[mt][nt] = __builtin_amdgcn_mfma_f32_16x16x32_bf16(
                        a[mt], bw[nt], acc0[mt][nt], 0, 0, 0);
        }
        __syncthreads();
#pragma unroll
        for (int nt = 0; nt < 4; ++nt) {
            const int ch = nt * 16 + mh;
            const float sc = sbn0[ch], sh = sbn0[64 + ch];
#pragma unroll
            for (int mt = 0; mt < 2; ++mt)
#pragma unroll
                for (int rr = 0; rr < 4; ++rr) {
                    const float v = fmaxf(fmaf(acc0[mt][nt][rr], sc, sh), 0.0f);
                    X[(mt * 16 + q * 4 + rr) * XP + ch] = f2bf(v);
                }
        }
        __syncthreads();
        // L1
        f32x4 acc1[2][4] = {};
#pragma unroll
        for (int ks = 0; ks < 2; ++ks) {
            bf16x8 a[2], bw[4];
#pragma unroll
            for (int mt = 0; mt < 2; ++mt)
                a[mt] = *(const bf16x8*)&X[(mt * 16 + mh) * XP + ks * 32 + q * 8];
#pragma unroll
            for (int nt = 0; nt < 4; ++nt)
                bw[nt] = *(const bf16x8*)&sw1[(nt * 16 + mh) * WP + ks * 32 + q * 8];
#pragma unroll
            for (int mt = 0; mt < 2; ++mt)
#pragma unroll
                for (int nt = 0; nt < 4; ++nt)
                    acc1[mt][nt] = __builtin_amdgcn_mfma_f32_16x16x32_bf16(
                        a[mt], bw[nt], acc1[mt][nt], 0, 0, 0);
        }
        __syncthreads();
#pragma unroll
        for (int nt = 0; nt < 4; ++nt) {
            const int ch = nt * 16 + mh;
            const float sc = sbn1[ch], sh = sbn1[64 + ch];
#pragma unroll
            for (int mt = 0; mt < 2; ++mt)
#pragma unroll
                for (int rr = 0; rr < 4; ++rr) {
                    const float v = fmaxf(fmaf(acc1[mt][nt][rr], sc, sh), 0.0f);
                    X[(mt * 16 + q * 4 + rr) * XP + ch] = f2bf(v);
                }
        }
        __syncthreads();
        // L2 + stats accumulate + per-group (32-row) max
        const int g = blockIdx.x * 16 + c * 4 + wid;
        bf16x8 a2[2][2];
#pragma unroll
        for (int mt = 0; mt < 2; ++mt)
#pragma unroll
            for (int ks = 0; ks < 2; ++ks)
                a2[mt][ks] = *(const bf16x8*)&X[(mt * 16 + mh) * XP + ks * 32 + q * 8];
#pragma unroll
        for (int nt = 0; nt < 8; ++nt) {
            f32x4 acc[2] = {};
#pragma unroll
            for (int ks = 0; ks < 2; ++ks) {
                const bf16x8 bw = *(const bf16x8*)&sw2[(nt * 16 + mh) * WP + ks * 32 + q * 8];
#pragma unroll
                for (int mt = 0; mt < 2; ++mt)
                    acc[mt] = __builtin_amdgcn_mfma_f32_16x16x32_bf16(
                        a2[mt][ks], bw, acc[mt], 0, 0, 0);
            }
            float m = -3.0e38f;
#pragma unroll
            for (int mt = 0; mt < 2; ++mt)
#pragma unroll
                for (int rr = 0; rr < 4; ++rr) {
                    const float v = acc[mt][rr];
                    sA[nt] += v;
                    qA[nt] = fmaf(v, v, qA[nt]);
                    m = fmaxf(m, v);
                }
            m = fmaxf(m, __shfl_xor(m, 16));
            m = fmaxf(m, __shfl_xor(m, 32));
            if (q == 0) gmax[(nt * 16 + mh) * 8192 + g] = m;
        }
    }
#pragma unroll
    for (int nt = 0; nt < 8; ++nt) {
        float s = sA[nt], qq = qA[nt];
        s += __shfl_xor(s, 16); qq += __shfl_xor(qq, 16);
        s += __shfl_xor(s, 32); qq += __shfl_xor(qq, 32);
        if (q == 0) {
            red[wid][nt * 16 + mh] = s;
            red[wid][128 + nt * 16 + mh] = qq;
        }
    }
    __syncthreads();
    atomicAdd(&stats[tid],
              red[0][tid] + red[1][tid] + red[2][tid] + red[3][tid]);
}

// ---------------------------------------------------------------------------
// final: bn2 computed inline from stats2; out2[b,o,s] = relu(bn2(gmax))
// ---------------------------------------------------------------------------
__global__ __launch_bounds__(256) void final_kernel(const float* __restrict__ gmax,
                                                    const float* __restrict__ stats2,
                                                    const float* __restrict__ g2,
                                                    const float* __restrict__ be2,
                                                    float* __restrict__ out2)
{
    __shared__ float sbn[256];
    const int tid = threadIdx.x;
    if (tid < 128) {
        const float inv = 1.0f / (float)NROWS;
        const float mean = stats2[tid] * inv;
        const float var = stats2[128 + tid] * inv - mean * mean;
        const float scale = g2[tid] * rsqrtf(var + 1e-5f);
        sbn[tid] = scale;
        sbn[128 + tid] = be2[tid] - mean * scale;
    }
    __syncthreads();
    const int t = blockIdx.x * 256 + tid;
    const int s = t & 1023;
    const int o = (t >> 10) & 127;
    const int b = t >> 17;
    const int g = (b << 10) | s;
    float v = gmax[o * 8192 + g];
    v = fmaf(v, sbn[o], sbn[128 + o]);
    out2[t] = fmaxf(v, 0.0f);
}

// ---------------------------------------------------------------------------
extern "C" void kernel_launch(void* const* d_in, const int* in_sizes, int n_in,
                              void* d_out, int out_size, void* d_ws, size_t ws_size,
                              hipStream_t stream)
{
    const float* xyz = (const float*)d_in[0];
    const float* pts = (const float*)d_in[1];
    const float* w0  = (const float*)d_in[2];
    const float* g0  = (const float*)d_in[4];
    const float* be0 = (const float*)d_in[5];
    const float* w1  = (const float*)d_in[6];
    const float* g1  = (const float*)d_in[8];
    const float* be1 = (const float*)d_in[9];
    const float* w2  = (const float*)d_in[10];
    const float* g2  = (const float*)d_in[12];
    const float* be2 = (const float*)d_in[13];

    float* out_xyz = (float*)d_out;             // (B,3,1024)
    float* out2    = out_xyz + 8 * 3 * NPOINT;  // (B,128,1024)

    char* wsb = (char*)d_ws;
    int*   idxbuf = (int*)(wsb + 32768);               // 262144 ints
    float* stats  = (float*)(wsb + 32768 + 1048576);   // 512 floats
    float* gmax   = stats + 1024;                      // 128*8192 floats

    float* mom    = stats;                              // 42 floats
    float* stats1 = stats + 128;
    float* stats2 = stats + 256;

    hipMemsetAsync(stats, 0, 512 * sizeof(float), stream);

    fps_kernel<<<8, 512, 0, stream>>>(xyz, out_xyz);
    ball_kernel<<<2048, 256, 0, stream>>>(xyz, pts, out_xyz, idxbuf, mom);
    mlp1_kernel<<<512, 256, 0, stream>>>(xyz, pts, out_xyz, idxbuf,
                                         w0, mom, g0, be0, w1, stats1);
    mlp2_kernel<<<512, 256, 0, stream>>>(xyz, pts, out_xyz, idxbuf,
                                         w0, mom, g0, be0, w1, stats1, g1, be1,
                                         w2, stats2, gmax);
    final_kernel<<<4096, 256, 0, stream>>>(gmax, stats2, g2, be2, out2);
}

// Round 14
// 795.878 us; speedup vs baseline: 1.0936x; 1.0936x over previous
//
#include <hip/hip_runtime.h>
#include <stdint.h>

#define NPTS   4096
#define NPOINT 1024
#define NSAMP  32
#define NROWS  262144   // B*NPOINT*NSAMP
#define RAD2   0.04f

typedef float v2f __attribute__((ext_vector_type(2)));
typedef __attribute__((ext_vector_type(8))) short bf16x8;
typedef __attribute__((ext_vector_type(4))) float f32x4;

// bf16 round-to-nearest-even
__device__ __forceinline__ unsigned short f2bf(float x) {
    unsigned u = __float_as_uint(x);
    return (unsigned short)((u + 0x7FFFu + ((u >> 16) & 1u)) >> 16);
}
__device__ __forceinline__ unsigned pack2bf(float a, float b) {
    return (unsigned)f2bf(a) | ((unsigned)f2bf(b) << 16);
}

// fused-DPP max helper (single-use feed -> v_max_f32_dpp)
#define DPPMAX(v, C)                                                           \
    fmaxf(__int_as_float(__builtin_amdgcn_update_dpp(                          \
              0, __float_as_int(v), C, 0xf, 0xf, true)),                       \
          (v))

// ---------------------------------------------------------------------------
// FPS: one block per batch, 256 threads (R10-validated structure).
// Distance chain bit-exact vs fp32 reference (packed fp32 IEEE-identical;
// contraction disabled). Reduce: fused v_max_f32_dpp chain -> readlane(63)
// -> ballot of bit-matching lanes -> wave-uniform scalar min over candidate
// lanes' thread-local argmax indices (peeled first iteration; mask provably
// non-empty) -> lane0 writes (value, ~minidx) key -> ONE barrier -> all
// threads select max of 4 keys -> pxyz[farthest] LDS read. Selection
// provably identical to the u64 lexicographic reduce (R4-R11).
// [R11 lesson: 512 thr (2 waves/SIMD) regresses — barrier arrival spread]
// ---------------------------------------------------------------------------
__global__ __launch_bounds__(256) void fps_kernel(const float* __restrict__ xyz,
                                                  float* __restrict__ outx)
{
    __shared__ __align__(16) float4 pxyz[NPTS];
    __shared__ __align__(16) float4 orec[NPOINT];
    __shared__ __align__(16) unsigned long long wkey[2][4];
    const int b = blockIdx.x, tid = threadIdx.x;
    const int lane = tid & 63, wid = tid >> 6;
    const float* base = xyz + b * 3 * NPTS;

    float Xs[16], Ys[16], Zs[16];
#pragma unroll
    for (int j = 0; j < 16; ++j) {
        const int n = j * 256 + tid;
        Xs[j] = base[n];
        Ys[j] = base[NPTS + n];
        Zs[j] = base[2 * NPTS + n];
        pxyz[n] = make_float4(Xs[j], Ys[j], Zs[j], 0.0f);
    }
    v2f X2[8], Y2[8], Z2[8], D2[8];
#pragma unroll
    for (int j = 0; j < 8; ++j) {
        X2[j] = (v2f){Xs[2 * j], Xs[2 * j + 1]};
        Y2[j] = (v2f){Ys[2 * j], Ys[2 * j + 1]};
        Z2[j] = (v2f){Zs[2 * j], Zs[2 * j + 1]};
        D2[j] = (v2f){1e10f, 1e10f};
    }
    __syncthreads();
    float4 c4 = pxyz[0];
    float cx = c4.x, cy = c4.y, cz = c4.z;

    for (int t = 0; t < NPOINT; ++t) {
        if (tid == 0) orec[t] = make_float4(cx, cy, cz, 0.0f);
        const v2f cxv = (v2f){cx, cx}, cyv = (v2f){cy, cy}, czv = (v2f){cz, cz};
        float bv = -1.0f; int bi = 0;
#pragma unroll
        for (int j = 0; j < 8; ++j) {
            v2f nd;
            {
#pragma clang fp contract(off)
                const v2f dx = X2[j] - cxv;
                const v2f dy = Y2[j] - cyv;
                const v2f dz = Z2[j] - czv;
                const v2f m0 = dx * dx;
                const v2f m1 = dy * dy;
                const v2f m2 = dz * dz;
                const v2f d = (m0 + m1) + m2;
                nd = __builtin_elementwise_min(D2[j], d);
            }
            D2[j] = nd;
            // ascending indices + strict > keep the first occurrence
            if (nd.x > bv) { bv = nd.x; bi = j * 512 + tid; }
            if (nd.y > bv) { bv = nd.y; bi = j * 512 + 256 + tid; }
        }
        // value-first fused-DPP max
        float rv = bv;                       // bv >= 0 (bound_ctrl 0-fill safe)
        rv = DPPMAX(rv, 0x111);              // row_shr:1
        rv = DPPMAX(rv, 0x112);              // row_shr:2
        rv = DPPMAX(rv, 0x114);              // row_shr:4
        rv = DPPMAX(rv, 0x118);              // row_shr:8
        rv = DPPMAX(rv, 0x142);              // row_bcast:15
        rv = DPPMAX(rv, 0x143);              // row_bcast:31
        const unsigned wmax =
            (unsigned)__builtin_amdgcn_readlane(__float_as_int(rv), 63);
        // index resolution: ballot (uniform sgpr mask) + scalar min over
        // matching lanes; mask provably non-empty; ties rare -> usually one
        // readlane. First iteration peeled, guarded while for the rest.
        unsigned long long mask = __ballot(__float_as_uint(bv) == wmax);
        unsigned best =
            (unsigned)__builtin_amdgcn_readlane(bi, (int)__builtin_ctzll(mask));
        mask &= mask - 1ull;
        while (mask) {
            const unsigned cand = (unsigned)__builtin_amdgcn_readlane(
                bi, (int)__builtin_ctzll(mask));
            best = cand < best ? cand : best;
            mask &= mask - 1ull;
        }
        if (lane == 0)
            wkey[t & 1][wid] = ((unsigned long long)wmax << 32) |
                               (unsigned)(~best);
        __syncthreads();
        const ulonglong2* wk = (const ulonglong2*)wkey[t & 1];
        const ulonglong2 ka = wk[0], kb = wk[1];
        unsigned long long kk = ka.x;
        if (ka.y > kk) kk = ka.y;
        if (kb.x > kk) kk = kb.x;
        if (kb.y > kk) kk = kb.y;
        const int farthest = (int)(~(unsigned)kk) & (NPTS - 1);
        c4 = pxyz[farthest];
        cx = c4.x; cy = c4.y; cz = c4.z;
    }
    __syncthreads();
    float* ox = outx + b * 3 * NPOINT;
    for (int i = tid; i < NPOINT; i += 256) {
        const float4 c = orec[i];
        ox[i]              = c.x;
        ox[NPOINT + i]     = c.y;
        ox[2 * NPOINT + i] = c.z;
    }
}

// ---------------------------------------------------------------------------
// Ball query + fused feature moments. One wave per query: first 32 in-radius
// indices (ascending); then lanes 0-31 gather their row's features and the
// block accumulates m1[6] / M2[36] (stats0 is bilinear in W0 -> bn0 derives
// from these 42 sums; computed inline in mlp kernels).
// ---------------------------------------------------------------------------
__global__ __launch_bounds__(256) void ball_kernel(const float* __restrict__ xyz,
                                                   const float* __restrict__ pts,
                                                   const float* __restrict__ outx,
                                                   int* __restrict__ idxbuf,
                                                   float* __restrict__ mom)
{
    __shared__ float red[4][42];
    const int tid = threadIdx.x;
    const int w = blockIdx.x * 4 + (tid >> 6);
    const int lane = tid & 63, wid = tid >> 6;
    const int b = w >> 10, s = w & 1023;
    const float* base = xyz + b * 3 * NPTS;
    const float cx = outx[b * 3 * NPOINT + s];
    const float cy = outx[b * 3 * NPOINT + NPOINT + s];
    const float cz = outx[b * 3 * NPOINT + 2 * NPOINT + s];
    const float sumS = __fadd_rn(__fadd_rn(__fmul_rn(cx, cx), __fmul_rn(cy, cy)),
                                 __fmul_rn(cz, cz));
    int cnt = 0, first_n = -1;
    int* myidx = idxbuf + w * NSAMP;

    for (int chunk = 0; chunk < NPTS / 64 && cnt < NSAMP; ++chunk) {
        const int n = chunk * 64 + lane;
        float nx = base[n], ny = base[NPTS + n], nz = base[2 * NPTS + n];
        float sumN = __fadd_rn(__fadd_rn(__fmul_rn(nx, nx), __fmul_rn(ny, ny)),
                               __fmul_rn(nz, nz));
        float dot = __fadd_rn(__fadd_rn(__fmul_rn(cx, nx), __fmul_rn(cy, ny)),
                              __fmul_rn(cz, nz));
        float sq = __fsub_rn(__fadd_rn(sumS, sumN), __fmul_rn(2.0f, dot));
        bool keep = (sq <= RAD2);
        unsigned long long mask = __ballot(keep);
        if (first_n < 0 && mask) first_n = chunk * 64 + (int)__builtin_ctzll(mask);
        int pos = cnt + __popcll(mask & ((1ull << lane) - 1ull));
        if (keep && pos < NSAMP) myidx[pos] = n;
        cnt += __popcll(mask);
    }
    if (cnt < NSAMP) {
        if (lane >= cnt && lane < NSAMP) myidx[lane] = first_n;
    }

    // ---- fused moments for this wave's 32 rows ----
    float m[42];
#pragma unroll
    for (int i = 0; i < 42; ++i) m[i] = 0.f;
    if (lane < 32) {
        const int idx = myidx[lane];
        const float* pb = pts + b * 3 * NPTS;
        float f[6];
        f[0] = base[idx] - cx;
        f[1] = base[NPTS + idx] - cy;
        f[2] = base[2 * NPTS + idx] - cz;
        f[3] = pb[idx];
        f[4] = pb[NPTS + idx];
        f[5] = pb[2 * NPTS + idx];
#pragma unroll
        for (int c = 0; c < 6; ++c) m[c] = f[c];
#pragma unroll
        for (int c = 0; c < 6; ++c)
#pragma unroll
            for (int d = 0; d < 6; ++d)
                m[6 + c * 6 + d] = f[c] * f[d];
    }
#pragma unroll
    for (int i = 0; i < 42; ++i) {
        float v = m[i];
        v += __shfl_xor(v, 1);  v += __shfl_xor(v, 2);  v += __shfl_xor(v, 4);
        v += __shfl_xor(v, 8);  v += __shfl_xor(v, 16); v += __shfl_xor(v, 32);
        m[i] = v;
    }
    if (lane == 0) {
#pragma unroll
        for (int i = 0; i < 42; ++i) red[wid][i] = m[i];
    }
    __syncthreads();
    if (tid < 42)
        atomicAdd(&mom[tid], red[0][tid] + red[1][tid] + red[2][tid] + red[3][tid]);
}

// ---------------------------------------------------------------------------
__device__ __forceinline__ void load_feats(const float* __restrict__ xyz,
                                           const float* __restrict__ pts,
                                           const float* __restrict__ outx,
                                           int r, int idx, float f[6])
{
    const int b = r >> 15;
    const int s = (r >> 5) & 1023;
    const float* xb = xyz + b * 3 * NPTS;
    const float* pb = pts + b * 3 * NPTS;
    const float* ob = outx + b * 3 * NPOINT;
    f[0] = xb[idx] - ob[s];
    f[1] = xb[NPTS + idx] - ob[NPOINT + s];
    f[2] = xb[2 * NPTS + idx] - ob[2 * NPOINT + s];
    f[3] = pb[idx];
    f[4] = pb[NPTS + idx];
    f[5] = pb[2 * NPTS + idx];
}

// bn0 from feature moments (biases cancel through BN shift; bilinear in W0)
__device__ __forceinline__ void compute_bn0(int o, const float* __restrict__ mom,
                                            const float* __restrict__ w0,
                                            const float* __restrict__ g,
                                            const float* __restrict__ be,
                                            float* __restrict__ sbn0)
{
    float w[6];
#pragma unroll
    for (int c = 0; c < 6; ++c) w[c] = w0[o * 6 + c];
    const float inv = 1.0f / (float)NROWS;
    float mean = 0.f;
#pragma unroll
    for (int c = 0; c < 6; ++c) mean = fmaf(w[c], mom[c], mean);
    mean *= inv;
    float ey2 = 0.f;
#pragma unroll
    for (int c = 0; c < 6; ++c) {
        float t = 0.f;
#pragma unroll
        for (int d = 0; d < 6; ++d) t = fmaf(w[d], mom[6 + c * 6 + d], t);
        ey2 = fmaf(w[c], t, ey2);
    }
    ey2 *= inv;
    const float var = ey2 - mean * mean;
    const float scale = g[o] * rsqrtf(var + 1e-5f);
    sbn0[o] = scale;
    sbn0[64 + o] = be[o] - mean * scale;
}

// ===========================================================================
// MFMA MLP kernels (R8-validated): 512 blocks x 512 rows (4 chunks of 128),
// weights staged once per block, stats in registers across chunks.
// mfma_f32_16x16x32_bf16: A[m=lane&15][k=q*8+j], B[k=q*8+j][n=lane&15],
// D[row=q*4+r][col=lane&15]  (q = lane>>4).
// ===========================================================================
#define XP  72
#define WP  72
#define W0P 40

// ---- mlp1: f -> L0 -> bn0(inline from moments) -> L1 -> stats1 --------------
__global__ __launch_bounds__(256, 2) void mlp1_kernel(
    const float* __restrict__ xyz, const float* __restrict__ pts,
    const float* __restrict__ outx, const int* __restrict__ idxbuf,
    const float* __restrict__ w0, const float* __restrict__ mom,
    const float* __restrict__ g0, const float* __restrict__ be0,
    const float* __restrict__ w1, float* __restrict__ stats)
{
    __shared__ __align__(16) unsigned short sw0[64 * W0P];
    __shared__ __align__(16) unsigned short sw1[64 * WP];
    __shared__ __align__(16) unsigned short xb[4][32 * XP];
    __shared__ float sbn0[128];
    __shared__ float red[4][128];
    const int tid = threadIdx.x, lane = tid & 63, wid = tid >> 6;

    for (int i = tid; i < 64 * W0P / 2; i += 256) ((unsigned*)sw0)[i] = 0;
    if (tid < 64) compute_bn0(tid, mom, w0, g0, be0, sbn0);
    __syncthreads();
    for (int i = tid; i < 192; i += 256) {
        const int o = i / 3, c = (i % 3) * 2;
        *(unsigned*)&sw0[o * W0P + c] = pack2bf(w0[o * 6 + c], w0[o * 6 + c + 1]);
    }
    for (int i = tid; i < 2048; i += 256) {
        const int o = i >> 5, k = (i & 31) * 2;
        *(unsigned*)&sw1[o * WP + k] = pack2bf(w1[o * 64 + k], w1[o * 64 + k + 1]);
    }

    const int mh = lane & 15, q = lane >> 4;
    unsigned short* X = xb[wid];
    const int rbase = blockIdx.x * 512 + wid * 32;
    float sA[4] = {0.f, 0.f, 0.f, 0.f}, qA[4] = {0.f, 0.f, 0.f, 0.f};

    for (int c = 0; c < 4; ++c) {
        __syncthreads();
        if (lane < 32) {
            const int r = rbase + c * 128 + lane;
            float f[6];
            load_feats(xyz, pts, outx, r, idxbuf[r], f);
            uint4* xq = (uint4*)&xb[wid][lane * XP];
            xq[0] = make_uint4(pack2bf(f[0], f[1]), pack2bf(f[2], f[3]),
                               pack2bf(f[4], f[5]), 0u);
            xq[1] = make_uint4(0u, 0u, 0u, 0u);
            xq[2] = make_uint4(0u, 0u, 0u, 0u);
            xq[3] = make_uint4(0u, 0u, 0u, 0u);
        }
        __syncthreads();
        // L0
        f32x4 acc0[2][4] = {};
        {
            bf16x8 a[2], bw[4];
#pragma unroll
            for (int mt = 0; mt < 2; ++mt)
                a[mt] = *(const bf16x8*)&X[(mt * 16 + mh) * XP + q * 8];
#pragma unroll
            for (int nt = 0; nt < 4; ++nt)
                bw[nt] = *(const bf16x8*)&sw0[(nt * 16 + mh) * W0P + q * 8];
#pragma unroll
            for (int mt = 0; mt < 2; ++mt)
#pragma unroll
                for (int nt = 0; nt < 4; ++nt)
                    acc0[mt][nt] = __builtin_amdgcn_mfma_f32_16x16x32_bf16(
                        a[mt], bw[nt], acc0[mt][nt], 0, 0, 0);
        }
        __syncthreads();
#pragma unroll
        for (int nt = 0; nt < 4; ++nt) {
            const int ch = nt * 16 + mh;
            const float sc = sbn0[ch], sh = sbn0[64 + ch];
#pragma unroll
            for (int mt = 0; mt < 2; ++mt)
#pragma unroll
                for (int rr = 0; rr < 4; ++rr) {
                    const float v = fmaxf(fmaf(acc0[mt][nt][rr], sc, sh), 0.0f);
                    X[(mt * 16 + q * 4 + rr) * XP + ch] = f2bf(v);
                }
        }
        __syncthreads();
        // L1
        f32x4 acc1[2][4] = {};
#pragma unroll
        for (int ks = 0; ks < 2; ++ks) {
            bf16x8 a[2], bw[4];
#pragma unroll
            for (int mt = 0; mt < 2; ++mt)
                a[mt] = *(const bf16x8*)&X[(mt * 16 + mh) * XP + ks * 32 + q * 8];
#pragma unroll
            for (int nt = 0; nt < 4; ++nt)
                bw[nt] = *(const bf16x8*)&sw1[(nt * 16 + mh) * WP + ks * 32 + q * 8];
#pragma unroll
            for (int mt = 0; mt < 2; ++mt)
#pragma unroll
                for (int nt = 0; nt < 4; ++nt)
                    acc1[mt][nt] = __builtin_amdgcn_mfma_f32_16x16x32_bf16(
                        a[mt], bw[nt], acc1[mt][nt], 0, 0, 0);
        }
#pragma unroll
        for (int nt = 0; nt < 4; ++nt)
#pragma unroll
            for (int mt = 0; mt < 2; ++mt)
#pragma unroll
                for (int rr = 0; rr < 4; ++rr) {
                    const float v = acc1[mt][nt][rr];
                    sA[nt] += v;
                    qA[nt] = fmaf(v, v, qA[nt]);
                }
    }
#pragma unroll
    for (int nt = 0; nt < 4; ++nt) {
        float s = sA[nt], qq = qA[nt];
        s += __shfl_xor(s, 16); qq += __shfl_xor(qq, 16);
        s += __shfl_xor(s, 32); qq += __shfl_xor(qq, 32);
        if (q == 0) {
            red[wid][nt * 16 + mh] = s;
            red[wid][64 + nt * 16 + mh] = qq;
        }
    }
    __syncthreads();
    if (tid < 128)
        atomicAdd(&stats[tid],
                  red[0][tid] + red[1][tid] + red[2][tid] + red[3][tid]);
}

// ---- mlp2: f -> L0 -> bn0 -> L1 -> bn1(inline) -> L2 -> stats2 + group max --
__global__ __launch_bounds__(256, 2) void mlp2_kernel(
    const float* __restrict__ xyz, const float* __restrict__ pts,
    const float* __restrict__ outx, const int* __restrict__ idxbuf,
    const float* __restrict__ w0, const float* __restrict__ mom,
    const float* __restrict__ g0, const float* __restrict__ be0,
    const float* __restrict__ w1, const float* __restrict__ stats1,
    const float* __restrict__ g1, const float* __restrict__ be1,
    const float* __restrict__ w2,
    float* __restrict__ stats, float* __restrict__ gmax)
{
    __shared__ __align__(16) unsigned short sw0[64 * W0P];
    __shared__ __align__(16) unsigned short sw1[64 * WP];
    __shared__ __align__(16) unsigned short sw2[128 * WP];
    __shared__ __align__(16) unsigned short xb[4][32 * XP];
    __shared__ float sbn0[128];
    __shared__ float sbn1[128];
    __shared__ float red[4][256];
    const int tid = threadIdx.x, lane = tid & 63, wid = tid >> 6;

    for (int i = tid; i < 64 * W0P / 2; i += 256) ((unsigned*)sw0)[i] = 0;
    if (tid < 64) {
        compute_bn0(tid, mom, w0, g0, be0, sbn0);
    } else if (tid < 128) {
        const int ch = tid - 64;
        const float inv = 1.0f / (float)NROWS;
        const float mean = stats1[ch] * inv;
        const float var = stats1[64 + ch] * inv - mean * mean;
        const float scale = g1[ch] * rsqrtf(var + 1e-5f);
        sbn1[ch] = scale;
        sbn1[64 + ch] = be1[ch] - mean * scale;
    }
    __syncthreads();
    for (int i = tid; i < 192; i += 256) {
        const int o = i / 3, c = (i % 3) * 2;
        *(unsigned*)&sw0[o * W0P + c] = pack2bf(w0[o * 6 + c], w0[o * 6 + c + 1]);
    }
    for (int i = tid; i < 2048; i += 256) {
        const int o = i >> 5, k = (i & 31) * 2;
        *(unsigned*)&sw1[o * WP + k] = pack2bf(w1[o * 64 + k], w1[o * 64 + k + 1]);
    }
    for (int i = tid; i < 4096; i += 256) {
        const int o = i >> 5, k = (i & 31) * 2;
        *(unsigned*)&sw2[o * WP + k] = pack2bf(w2[o * 64 + k], w2[o * 64 + k + 1]);
    }

    const int mh = lane & 15, q = lane >> 4;
    unsigned short* X = xb[wid];
    const int rbase = blockIdx.x * 512 + wid * 32;
    float sA[8], qA[8];
#pragma unroll
    for (int i = 0; i < 8; ++i) { sA[i] = 0.f; qA[i] = 0.f; }

    for (int c = 0; c < 4; ++c) {
        __syncthreads();
        if (lane < 32) {
            const int r = rbase + c * 128 + lane;
            float f[6];
            load_feats(xyz, pts, outx, r, idxbuf[r], f);
            uint4* xq = (uint4*)&xb[wid][lane * XP];
            xq[0] = make_uint4(pack2bf(f[0], f[1]), pack2bf(f[2], f[3]),
                               pack2bf(f[4], f[5]), 0u);
            xq[1] = make_uint4(0u, 0u, 0u, 0u);
            xq[2] = make_uint4(0u, 0u, 0u, 0u);
            xq[3] = make_uint4(0u, 0u, 0u, 0u);
        }
        __syncthreads();
        // L0
        f32x4 acc0[2][4] = {};
        {
            bf16x8 a[2], bw[4];
#pragma unroll
            for (int mt = 0; mt < 2; ++mt)
                a[mt] = *(const bf16x8*)&X[(mt * 16 + mh) * XP + q * 8];
#pragma unroll
            for (int nt = 0; nt < 4; ++nt)
                bw[nt] = *(const bf16x8*)&sw0[(nt * 16 + mh) * W0P + q * 8];
#pragma unroll
            for (int mt = 0; mt < 2; ++mt)
#pragma unroll
                for (int nt = 0; nt < 4; ++nt)
                    acc0[mt][nt] = __builtin_amdgcn_mfma_f32_16x16x32_bf16(
                        a[mt], bw[nt], acc0[mt][nt], 0, 0, 0);
        }
        __syncthreads();
#pragma unroll
        for (int nt = 0; nt < 4; ++nt) {
            const int ch = nt * 16 + mh;
            const float sc = sbn0[ch], sh = sbn0[64 + ch];
#pragma unroll
            for (int mt = 0; mt < 2; ++mt)
#pragma unroll
                for (int rr = 0; rr < 4; ++rr) {
                    const float v = fmaxf(fmaf(acc0[mt][nt][rr], sc, sh), 0.0f);
                    X[(mt * 16 + q * 4 + rr) * XP + ch] = f2bf(v);
                }
        }
        __syncthreads();
        // L1
        f32x4 acc1[2][4] = {};
#pragma unroll
        for (int ks = 0; ks < 2; ++ks) {
            bf16x8 a[2], bw[4];
#pragma unroll
            for (int mt = 0; mt < 2; ++mt)
                a[mt] = *(const bf16x8*)&X[(mt * 16 + mh) * XP + ks * 32 + q * 8];
#pragma unroll
            for (int nt = 0; nt < 4; ++nt)
                bw[nt] = *(const bf16x8*)&sw1[(nt * 16 + mh) * WP + ks * 32 + q * 8];
#pragma unroll
            for (int mt = 0; mt < 2; ++mt)
#pragma unroll
                for (int nt = 0; nt < 4; ++nt)
                    acc1[mt][nt] = __builtin_amdgcn_mfma_f32_16x16x32_bf16(
                        a[mt], bw[nt], acc1[mt][nt], 0, 0, 0);
        }
        __syncthreads();
#pragma unroll
        for (int nt = 0; nt < 4; ++nt) {
            const int ch = nt * 16 + mh;
            const float sc = sbn1[ch], sh = sbn1[64 + ch];
#pragma unroll
            for (int mt = 0; mt < 2; ++mt)
#pragma unroll
                for (int rr = 0; rr < 4; ++rr) {
                    const float v = fmaxf(fmaf(acc1[mt][nt][rr], sc, sh), 0.0f);
                    X[(mt * 16 + q * 4 + rr) * XP + ch] = f2bf(v);
                }
        }
        __syncthreads();
        // L2 + stats accumulate + per-group (32-row) max
        const int g = blockIdx.x * 16 + c * 4 + wid;
        bf16x8 a2[2][2];
#pragma unroll
        for (int mt = 0; mt < 2; ++mt)
#pragma unroll
            for (int ks = 0; ks < 2; ++ks)
                a2[mt][ks] = *(const bf16x8*)&X[(mt * 16 + mh) * XP + ks * 32 + q * 8];
#pragma unroll
        for (int nt = 0; nt < 8; ++nt) {
            f32x4 acc[2] = {};
#pragma unroll
            for (int ks = 0; ks < 2; ++ks) {
                const bf16x8 bw = *(const bf16x8*)&sw2[(nt * 16 + mh) * WP + ks * 32 + q * 8];
#pragma unroll
                for (int mt = 0; mt < 2; ++mt)
                    acc[mt] = __builtin_amdgcn_mfma_f32_16x16x32_bf16(
                        a2[mt][ks], bw, acc[mt], 0, 0, 0);
            }
            float m = -3.0e38f;
#pragma unroll
            for (int mt = 0; mt < 2; ++mt)
#pragma unroll
                for (int rr = 0; rr < 4; ++rr) {
                    const float v = acc[mt][rr];
                    sA[nt] += v;
                    qA[nt] = fmaf(v, v, qA[nt]);
                    m = fmaxf(m, v);
                }
            m = fmaxf(m, __shfl_xor(m, 16));
            m = fmaxf(m, __shfl_xor(m, 32));
            if (q == 0) gmax[(nt * 16 + mh) * 8192 + g] = m;
        }
    }
#pragma unroll
    for (int nt = 0; nt < 8; ++nt) {
        float s = sA[nt], qq = qA[nt];
        s += __shfl_xor(s, 16); qq += __shfl_xor(qq, 16);
        s += __shfl_xor(s, 32); qq += __shfl_xor(qq, 32);
        if (q == 0) {
            red[wid][nt * 16 + mh] = s;
            red[wid][128 + nt * 16 + mh] = qq;
        }
    }
    __syncthreads();
    atomicAdd(&stats[tid],
              red[0][tid] + red[1][tid] + red[2][tid] + red[3][tid]);
}

// ---------------------------------------------------------------------------
// final: bn2 computed inline from stats2; out2[b,o,s] = relu(bn2(gmax))
// ---------------------------------------------------------------------------
__global__ __launch_bounds__(256) void final_kernel(const float* __restrict__ gmax,
                                                    const float* __restrict__ stats2,
                                                    const float* __restrict__ g2,
                                                    const float* __restrict__ be2,
                                                    float* __restrict__ out2)
{
    __shared__ float sbn[256];
    const int tid = threadIdx.x;
    if (tid < 128) {
        const float inv = 1.0f / (float)NROWS;
        const float mean = stats2[tid] * inv;
        const float var = stats2[128 + tid] * inv - mean * mean;
        const float scale = g2[tid] * rsqrtf(var + 1e-5f);
        sbn[tid] = scale;
        sbn[128 + tid] = be2[tid] - mean * scale;
    }
    __syncthreads();
    const int t = blockIdx.x * 256 + tid;
    const int s = t & 1023;
    const int o = (t >> 10) & 127;
    const int b = t >> 17;
    const int g = (b << 10) | s;
    float v = gmax[o * 8192 + g];
    v = fmaf(v, sbn[o], sbn[128 + o]);
    out2[t] = fmaxf(v, 0.0f);
}

// ---------------------------------------------------------------------------
extern "C" void kernel_launch(void* const* d_in, const int* in_sizes, int n_in,
                              void* d_out, int out_size, void* d_ws, size_t ws_size,
                              hipStream_t stream)
{
    const float* xyz = (const float*)d_in[0];
    const float* pts = (const float*)d_in[1];
    const float* w0  = (const float*)d_in[2];
    const float* g0  = (const float*)d_in[4];
    const float* be0 = (const float*)d_in[5];
    const float* w1  = (const float*)d_in[6];
    const float* g1  = (const float*)d_in[8];
    const float* be1 = (const float*)d_in[9];
    const float* w2  = (const float*)d_in[10];
    const float* g2  = (const float*)d_in[12];
    const float* be2 = (const float*)d_in[13];

    float* out_xyz = (float*)d_out;             // (B,3,1024)
    float* out2    = out_xyz + 8 * 3 * NPOINT;  // (B,128,1024)

    char* wsb = (char*)d_ws;
    int*   idxbuf = (int*)(wsb + 32768);               // 262144 ints
    float* stats  = (float*)(wsb + 32768 + 1048576);   // 512 floats
    float* gmax   = stats + 1024;                      // 128*8192 floats

    float* mom    = stats;                              // 42 floats
    float* stats1 = stats + 128;
    float* stats2 = stats + 256;

    hipMemsetAsync(stats, 0, 512 * sizeof(float), stream);

    fps_kernel<<<8, 256, 0, stream>>>(xyz, out_xyz);
    ball_kernel<<<2048, 256, 0, stream>>>(xyz, pts, out_xyz, idxbuf, mom);
    mlp1_kernel<<<512, 256, 0, stream>>>(xyz, pts, out_xyz, idxbuf,
                                         w0, mom, g0, be0, w1, stats1);
    mlp2_kernel<<<512, 256, 0, stream>>>(xyz, pts, out_xyz, idxbuf,
                                         w0, mom, g0, be0, w1, stats1, g1, be1,
                                         w2, stats2, gmax);
    final_kernel<<<4096, 256, 0, stream>>>(gmax, stats2, g2, be2, out2);
}

// Round 15
// 794.538 us; speedup vs baseline: 1.0954x; 1.0017x over previous
//
#include <hip/hip_runtime.h>
#include <stdint.h>

#define NPTS   4096
#define NPOINT 1024
#define NSAMP  32
#define NROWS  262144   // B*NPOINT*NSAMP
#define RAD2   0.04f

typedef float v2f __attribute__((ext_vector_type(2)));
typedef __attribute__((ext_vector_type(8))) short bf16x8;
typedef __attribute__((ext_vector_type(4))) float f32x4;

// bf16 round-to-nearest-even
__device__ __forceinline__ unsigned short f2bf(float x) {
    unsigned u = __float_as_uint(x);
    return (unsigned short)((u + 0x7FFFu + ((u >> 16) & 1u)) >> 16);
}
__device__ __forceinline__ unsigned pack2bf(float a, float b) {
    return (unsigned)f2bf(a) | ((unsigned)f2bf(b) << 16);
}

// fused-DPP max helper (single-use feed -> v_max_f32_dpp)
#define DPPMAX(v, C)                                                           \
    fmaxf(__int_as_float(__builtin_amdgcn_update_dpp(                          \
              0, __float_as_int(v), C, 0xf, 0xf, true)),                       \
          (v))

// ---------------------------------------------------------------------------
// FPS: frozen at R14 state (587us; 5 structural variants plateaued).
// ---------------------------------------------------------------------------
__global__ __launch_bounds__(256) void fps_kernel(const float* __restrict__ xyz,
                                                  float* __restrict__ outx)
{
    __shared__ __align__(16) float4 pxyz[NPTS];
    __shared__ __align__(16) float4 orec[NPOINT];
    __shared__ __align__(16) unsigned long long wkey[2][4];
    const int b = blockIdx.x, tid = threadIdx.x;
    const int lane = tid & 63, wid = tid >> 6;
    const float* base = xyz + b * 3 * NPTS;

    float Xs[16], Ys[16], Zs[16];
#pragma unroll
    for (int j = 0; j < 16; ++j) {
        const int n = j * 256 + tid;
        Xs[j] = base[n];
        Ys[j] = base[NPTS + n];
        Zs[j] = base[2 * NPTS + n];
        pxyz[n] = make_float4(Xs[j], Ys[j], Zs[j], 0.0f);
    }
    v2f X2[8], Y2[8], Z2[8], D2[8];
#pragma unroll
    for (int j = 0; j < 8; ++j) {
        X2[j] = (v2f){Xs[2 * j], Xs[2 * j + 1]};
        Y2[j] = (v2f){Ys[2 * j], Ys[2 * j + 1]};
        Z2[j] = (v2f){Zs[2 * j], Zs[2 * j + 1]};
        D2[j] = (v2f){1e10f, 1e10f};
    }
    __syncthreads();
    float4 c4 = pxyz[0];
    float cx = c4.x, cy = c4.y, cz = c4.z;

    for (int t = 0; t < NPOINT; ++t) {
        if (tid == 0) orec[t] = make_float4(cx, cy, cz, 0.0f);
        const v2f cxv = (v2f){cx, cx}, cyv = (v2f){cy, cy}, czv = (v2f){cz, cz};
        float bv = -1.0f; int bi = 0;
#pragma unroll
        for (int j = 0; j < 8; ++j) {
            v2f nd;
            {
#pragma clang fp contract(off)
                const v2f dx = X2[j] - cxv;
                const v2f dy = Y2[j] - cyv;
                const v2f dz = Z2[j] - czv;
                const v2f m0 = dx * dx;
                const v2f m1 = dy * dy;
                const v2f m2 = dz * dz;
                const v2f d = (m0 + m1) + m2;
                nd = __builtin_elementwise_min(D2[j], d);
            }
            D2[j] = nd;
            // ascending indices + strict > keep the first occurrence
            if (nd.x > bv) { bv = nd.x; bi = j * 512 + tid; }
            if (nd.y > bv) { bv = nd.y; bi = j * 512 + 256 + tid; }
        }
        // value-first fused-DPP max
        float rv = bv;                       // bv >= 0 (bound_ctrl 0-fill safe)
        rv = DPPMAX(rv, 0x111);              // row_shr:1
        rv = DPPMAX(rv, 0x112);              // row_shr:2
        rv = DPPMAX(rv, 0x114);              // row_shr:4
        rv = DPPMAX(rv, 0x118);              // row_shr:8
        rv = DPPMAX(rv, 0x142);              // row_bcast:15
        rv = DPPMAX(rv, 0x143);              // row_bcast:31
        const unsigned wmax =
            (unsigned)__builtin_amdgcn_readlane(__float_as_int(rv), 63);
        // index resolution: ballot + scalar min over matching lanes
        unsigned long long mask = __ballot(__float_as_uint(bv) == wmax);
        unsigned best =
            (unsigned)__builtin_amdgcn_readlane(bi, (int)__builtin_ctzll(mask));
        mask &= mask - 1ull;
        while (mask) {
            const unsigned cand = (unsigned)__builtin_amdgcn_readlane(
                bi, (int)__builtin_ctzll(mask));
            best = cand < best ? cand : best;
            mask &= mask - 1ull;
        }
        if (lane == 0)
            wkey[t & 1][wid] = ((unsigned long long)wmax << 32) |
                               (unsigned)(~best);
        __syncthreads();
        const ulonglong2* wk = (const ulonglong2*)wkey[t & 1];
        const ulonglong2 ka = wk[0], kb = wk[1];
        unsigned long long kk = ka.x;
        if (ka.y > kk) kk = ka.y;
        if (kb.x > kk) kk = kb.x;
        if (kb.y > kk) kk = kb.y;
        const int farthest = (int)(~(unsigned)kk) & (NPTS - 1);
        c4 = pxyz[farthest];
        cx = c4.x; cy = c4.y; cz = c4.z;
    }
    __syncthreads();
    float* ox = outx + b * 3 * NPOINT;
    for (int i = tid; i < NPOINT; i += 256) {
        const float4 c = orec[i];
        ox[i]              = c.x;
        ox[NPOINT + i]     = c.y;
        ox[2 * NPOINT + i] = c.z;
    }
}

// ---------------------------------------------------------------------------
// Ball query + fused moments + packed-bf16 feature store. One wave per query:
// first 32 in-radius indices; lanes 0-31 gather their row's features once,
// accumulate m1[6]/M2[36], AND store the row's packed bf16 uint4 (exactly the
// LDS A-tile format) to featbuf -> mlp kernels never gather again.
// ---------------------------------------------------------------------------
__global__ __launch_bounds__(256) void ball_kernel(const float* __restrict__ xyz,
                                                   const float* __restrict__ pts,
                                                   const float* __restrict__ outx,
                                                   int* __restrict__ idxbuf,
                                                   float* __restrict__ mom,
                                                   uint4* __restrict__ featbuf)
{
    __shared__ float red[4][42];
    const int tid = threadIdx.x;
    const int w = blockIdx.x * 4 + (tid >> 6);
    const int lane = tid & 63, wid = tid >> 6;
    const int b = w >> 10, s = w & 1023;
    const float* base = xyz + b * 3 * NPTS;
    const float cx = outx[b * 3 * NPOINT + s];
    const float cy = outx[b * 3 * NPOINT + NPOINT + s];
    const float cz = outx[b * 3 * NPOINT + 2 * NPOINT + s];
    const float sumS = __fadd_rn(__fadd_rn(__fmul_rn(cx, cx), __fmul_rn(cy, cy)),
                                 __fmul_rn(cz, cz));
    int cnt = 0, first_n = -1;
    int* myidx = idxbuf + w * NSAMP;

    for (int chunk = 0; chunk < NPTS / 64 && cnt < NSAMP; ++chunk) {
        const int n = chunk * 64 + lane;
        float nx = base[n], ny = base[NPTS + n], nz = base[2 * NPTS + n];
        float sumN = __fadd_rn(__fadd_rn(__fmul_rn(nx, nx), __fmul_rn(ny, ny)),
                               __fmul_rn(nz, nz));
        float dot = __fadd_rn(__fadd_rn(__fmul_rn(cx, nx), __fmul_rn(cy, ny)),
                              __fmul_rn(cz, nz));
        float sq = __fsub_rn(__fadd_rn(sumS, sumN), __fmul_rn(2.0f, dot));
        bool keep = (sq <= RAD2);
        unsigned long long mask = __ballot(keep);
        if (first_n < 0 && mask) first_n = chunk * 64 + (int)__builtin_ctzll(mask);
        int pos = cnt + __popcll(mask & ((1ull << lane) - 1ull));
        if (keep && pos < NSAMP) myidx[pos] = n;
        cnt += __popcll(mask);
    }
    if (cnt < NSAMP) {
        if (lane >= cnt && lane < NSAMP) myidx[lane] = first_n;
    }

    // ---- fused moments + feature store for this wave's 32 rows ----
    float m[42];
#pragma unroll
    for (int i = 0; i < 42; ++i) m[i] = 0.f;
    if (lane < 32) {
        const int idx = myidx[lane];
        const float* pb = pts + b * 3 * NPTS;
        float f[6];
        f[0] = base[idx] - cx;
        f[1] = base[NPTS + idx] - cy;
        f[2] = base[2 * NPTS + idx] - cz;
        f[3] = pb[idx];
        f[4] = pb[NPTS + idx];
        f[5] = pb[2 * NPTS + idx];
        featbuf[w * NSAMP + lane] =
            make_uint4(pack2bf(f[0], f[1]), pack2bf(f[2], f[3]),
                       pack2bf(f[4], f[5]), 0u);
#pragma unroll
        for (int c = 0; c < 6; ++c) m[c] = f[c];
#pragma unroll
        for (int c = 0; c < 6; ++c)
#pragma unroll
            for (int d = 0; d < 6; ++d)
                m[6 + c * 6 + d] = f[c] * f[d];
    }
#pragma unroll
    for (int i = 0; i < 42; ++i) {
        float v = m[i];
        v += __shfl_xor(v, 1);  v += __shfl_xor(v, 2);  v += __shfl_xor(v, 4);
        v += __shfl_xor(v, 8);  v += __shfl_xor(v, 16); v += __shfl_xor(v, 32);
        m[i] = v;
    }
    if (lane == 0) {
#pragma unroll
        for (int i = 0; i < 42; ++i) red[wid][i] = m[i];
    }
    __syncthreads();
    if (tid < 42)
        atomicAdd(&mom[tid], red[0][tid] + red[1][tid] + red[2][tid] + red[3][tid]);
}

// bn0 from feature moments (biases cancel through BN shift; bilinear in W0)
__device__ __forceinline__ void compute_bn0(int o, const float* __restrict__ mom,
                                            const float* __restrict__ w0,
                                            const float* __restrict__ g,
                                            const float* __restrict__ be,
                                            float* __restrict__ sbn0)
{
    float w[6];
#pragma unroll
    for (int c = 0; c < 6; ++c) w[c] = w0[o * 6 + c];
    const float inv = 1.0f / (float)NROWS;
    float mean = 0.f;
#pragma unroll
    for (int c = 0; c < 6; ++c) mean = fmaf(w[c], mom[c], mean);
    mean *= inv;
    float ey2 = 0.f;
#pragma unroll
    for (int c = 0; c < 6; ++c) {
        float t = 0.f;
#pragma unroll
        for (int d = 0; d < 6; ++d) t = fmaf(w[d], mom[6 + c * 6 + d], t);
        ey2 = fmaf(w[c], t, ey2);
    }
    ey2 *= inv;
    const float var = ey2 - mean * mean;
    const float scale = g[o] * rsqrtf(var + 1e-5f);
    sbn0[o] = scale;
    sbn0[64 + o] = be[o] - mean * scale;
}

// ===========================================================================
// MFMA MLP kernels (R8-validated structure): 512 blocks x 512 rows (4 chunks
// of 128), weights staged once per block, stats in registers across chunks.
// A-tile rows now loaded as ONE coalesced uint4 from featbuf (no gather).
// mfma_f32_16x16x32_bf16: A[m=lane&15][k=q*8+j], B[k=q*8+j][n=lane&15],
// D[row=q*4+r][col=lane&15]  (q = lane>>4).
// ===========================================================================
#define XP  72
#define WP  72
#define W0P 40

// ---- mlp1: feat -> L0 -> bn0(inline from moments) -> L1 -> stats1 -----------
__global__ __launch_bounds__(256, 2) void mlp1_kernel(
    const uint4* __restrict__ featbuf,
    const float* __restrict__ w0, const float* __restrict__ mom,
    const float* __restrict__ g0, const float* __restrict__ be0,
    const float* __restrict__ w1, float* __restrict__ stats)
{
    __shared__ __align__(16) unsigned short sw0[64 * W0P];
    __shared__ __align__(16) unsigned short sw1[64 * WP];
    __shared__ __align__(16) unsigned short xb[4][32 * XP];
    __shared__ float sbn0[128];
    __shared__ float red[4][128];
    const int tid = threadIdx.x, lane = tid & 63, wid = tid >> 6;

    for (int i = tid; i < 64 * W0P / 2; i += 256) ((unsigned*)sw0)[i] = 0;
    if (tid < 64) compute_bn0(tid, mom, w0, g0, be0, sbn0);
    __syncthreads();
    for (int i = tid; i < 192; i += 256) {
        const int o = i / 3, c = (i % 3) * 2;
        *(unsigned*)&sw0[o * W0P + c] = pack2bf(w0[o * 6 + c], w0[o * 6 + c + 1]);
    }
    for (int i = tid; i < 2048; i += 256) {
        const int o = i >> 5, k = (i & 31) * 2;
        *(unsigned*)&sw1[o * WP + k] = pack2bf(w1[o * 64 + k], w1[o * 64 + k + 1]);
    }

    const int mh = lane & 15, q = lane >> 4;
    unsigned short* X = xb[wid];
    const int rbase = blockIdx.x * 512 + wid * 32;
    float sA[4] = {0.f, 0.f, 0.f, 0.f}, qA[4] = {0.f, 0.f, 0.f, 0.f};

    for (int c = 0; c < 4; ++c) {
        __syncthreads();
        if (lane < 32) {
            const int r = rbase + c * 128 + lane;
            uint4* xq = (uint4*)&xb[wid][lane * XP];
            xq[0] = featbuf[r];
            xq[1] = make_uint4(0u, 0u, 0u, 0u);
            xq[2] = make_uint4(0u, 0u, 0u, 0u);
            xq[3] = make_uint4(0u, 0u, 0u, 0u);
        }
        __syncthreads();
        // L0
        f32x4 acc0[2][4] = {};
        {
            bf16x8 a[2], bw[4];
#pragma unroll
            for (int mt = 0; mt < 2; ++mt)
                a[mt] = *(const bf16x8*)&X[(mt * 16 + mh) * XP + q * 8];
#pragma unroll
            for (int nt = 0; nt < 4; ++nt)
                bw[nt] = *(const bf16x8*)&sw0[(nt * 16 + mh) * W0P + q * 8];
#pragma unroll
            for (int mt = 0; mt < 2; ++mt)
#pragma unroll
                for (int nt = 0; nt < 4; ++nt)
                    acc0[mt][nt] = __builtin_amdgcn_mfma_f32_16x16x32_bf16(
                        a[mt], bw[nt], acc0[mt][nt], 0, 0, 0);
        }
        __syncthreads();
#pragma unroll
        for (int nt = 0; nt < 4; ++nt) {
            const int ch = nt * 16 + mh;
            const float sc = sbn0[ch], sh = sbn0[64 + ch];
#pragma unroll
            for (int mt = 0; mt < 2; ++mt)
#pragma unroll
                for (int rr = 0; rr < 4; ++rr) {
                    const float v = fmaxf(fmaf(acc0[mt][nt][rr], sc, sh), 0.0f);
                    X[(mt * 16 + q * 4 + rr) * XP + ch] = f2bf(v);
                }
        }
        __syncthreads();
        // L1
        f32x4 acc1[2][4] = {};
#pragma unroll
        for (int ks = 0; ks < 2; ++ks) {
            bf16x8 a[2], bw[4];
#pragma unroll
            for (int mt = 0; mt < 2; ++mt)
                a[mt] = *(const bf16x8*)&X[(mt * 16 + mh) * XP + ks * 32 + q * 8];
#pragma unroll
            for (int nt = 0; nt < 4; ++nt)
                bw[nt] = *(const bf16x8*)&sw1[(nt * 16 + mh) * WP + ks * 32 + q * 8];
#pragma unroll
            for (int mt = 0; mt < 2; ++mt)
#pragma unroll
                for (int nt = 0; nt < 4; ++nt)
                    acc1[mt][nt] = __builtin_amdgcn_mfma_f32_16x16x32_bf16(
                        a[mt], bw[nt], acc1[mt][nt], 0, 0, 0);
        }
#pragma unroll
        for (int nt = 0; nt < 4; ++nt)
#pragma unroll
            for (int mt = 0; mt < 2; ++mt)
#pragma unroll
                for (int rr = 0; rr < 4; ++rr) {
                    const float v = acc1[mt][nt][rr];
                    sA[nt] += v;
                    qA[nt] = fmaf(v, v, qA[nt]);
                }
    }
#pragma unroll
    for (int nt = 0; nt < 4; ++nt) {
        float s = sA[nt], qq = qA[nt];
        s += __shfl_xor(s, 16); qq += __shfl_xor(qq, 16);
        s += __shfl_xor(s, 32); qq += __shfl_xor(qq, 32);
        if (q == 0) {
            red[wid][nt * 16 + mh] = s;
            red[wid][64 + nt * 16 + mh] = qq;
        }
    }
    __syncthreads();
    if (tid < 128)
        atomicAdd(&stats[tid],
                  red[0][tid] + red[1][tid] + red[2][tid] + red[3][tid]);
}

// ---- mlp2: feat -> L0 -> bn0 -> L1 -> bn1(inline) -> L2 -> stats2 + max -----
__global__ __launch_bounds__(256, 2) void mlp2_kernel(
    const uint4* __restrict__ featbuf,
    const float* __restrict__ w0, const float* __restrict__ mom,
    const float* __restrict__ g0, const float* __restrict__ be0,
    const float* __restrict__ w1, const float* __restrict__ stats1,
    const float* __restrict__ g1, const float* __restrict__ be1,
    const float* __restrict__ w2,
    float* __restrict__ stats, float* __restrict__ gmax)
{
    __shared__ __align__(16) unsigned short sw0[64 * W0P];
    __shared__ __align__(16) unsigned short sw1[64 * WP];
    __shared__ __align__(16) unsigned short sw2[128 * WP];
    __shared__ __align__(16) unsigned short xb[4][32 * XP];
    __shared__ float sbn0[128];
    __shared__ float sbn1[128];
    __shared__ float red[4][256];
    const int tid = threadIdx.x, lane = tid & 63, wid = tid >> 6;

    for (int i = tid; i < 64 * W0P / 2; i += 256) ((unsigned*)sw0)[i] = 0;
    if (tid < 64) {
        compute_bn0(tid, mom, w0, g0, be0, sbn0);
    } else if (tid < 128) {
        const int ch = tid - 64;
        const float inv = 1.0f / (float)NROWS;
        const float mean = stats1[ch] * inv;
        const float var = stats1[64 + ch] * inv - mean * mean;
        const float scale = g1[ch] * rsqrtf(var + 1e-5f);
        sbn1[ch] = scale;
        sbn1[64 + ch] = be1[ch] - mean * scale;
    }
    __syncthreads();
    for (int i = tid; i < 192; i += 256) {
        const int o = i / 3, c = (i % 3) * 2;
        *(unsigned*)&sw0[o * W0P + c] = pack2bf(w0[o * 6 + c], w0[o * 6 + c + 1]);
    }
    for (int i = tid; i < 2048; i += 256) {
        const int o = i >> 5, k = (i & 31) * 2;
        *(unsigned*)&sw1[o * WP + k] = pack2bf(w1[o * 64 + k], w1[o * 64 + k + 1]);
    }
    for (int i = tid; i < 4096; i += 256) {
        const int o = i >> 5, k = (i & 31) * 2;
        *(unsigned*)&sw2[o * WP + k] = pack2bf(w2[o * 64 + k], w2[o * 64 + k + 1]);
    }

    const int mh = lane & 15, q = lane >> 4;
    unsigned short* X = xb[wid];
    const int rbase = blockIdx.x * 512 + wid * 32;
    float sA[8], qA[8];
#pragma unroll
    for (int i = 0; i < 8; ++i) { sA[i] = 0.f; qA[i] = 0.f; }

    for (int c = 0; c < 4; ++c) {
        __syncthreads();
        if (lane < 32) {
            const int r = rbase + c * 128 + lane;
            uint4* xq = (uint4*)&xb[wid][lane * XP];
            xq[0] = featbuf[r];
            xq[1] = make_uint4(0u, 0u, 0u, 0u);
            xq[2] = make_uint4(0u, 0u, 0u, 0u);
            xq[3] = make_uint4(0u, 0u, 0u, 0u);
        }
        __syncthreads();
        // L0
        f32x4 acc0[2][4] = {};
        {
            bf16x8 a[2], bw[4];
#pragma unroll
            for (int mt = 0; mt < 2; ++mt)
                a[mt] = *(const bf16x8*)&X[(mt * 16 + mh) * XP + q * 8];
#pragma unroll
            for (int nt = 0; nt < 4; ++nt)
                bw[nt] = *(const bf16x8*)&sw0[(nt * 16 + mh) * W0P + q * 8];
#pragma unroll
            for (int mt = 0; mt < 2; ++mt)
#pragma unroll
                for (int nt = 0; nt < 4; ++nt)
                    acc0[mt][nt] = __builtin_amdgcn_mfma_f32_16x16x32_bf16(
                        a[mt], bw[nt], acc0[mt][nt], 0, 0, 0);
        }
        __syncthreads();
#pragma unroll
        for (int nt = 0; nt < 4; ++nt) {
            const int ch = nt * 16 + mh;
            const float sc = sbn0[ch], sh = sbn0[64 + ch];
#pragma unroll
            for (int mt = 0; mt < 2; ++mt)
#pragma unroll
                for (int rr = 0; rr < 4; ++rr) {
                    const float v = fmaxf(fmaf(acc0[mt][nt][rr], sc, sh), 0.0f);
                    X[(mt * 16 + q * 4 + rr) * XP + ch] = f2bf(v);
                }
        }
        __syncthreads();
        // L1
        f32x4 acc1[2][4] = {};
#pragma unroll
        for (int ks = 0; ks < 2; ++ks) {
            bf16x8 a[2], bw[4];
#pragma unroll
            for (int mt = 0; mt < 2; ++mt)
                a[mt] = *(const bf16x8*)&X[(mt * 16 + mh) * XP + ks * 32 + q * 8];
#pragma unroll
            for (int nt = 0; nt < 4; ++nt)
                bw[nt] = *(const bf16x8*)&sw1[(nt * 16 + mh) * WP + ks * 32 + q * 8];
#pragma unroll
            for (int mt = 0; mt < 2; ++mt)
#pragma unroll
                for (int nt = 0; nt < 4; ++nt)
                    acc1[mt][nt] = __builtin_amdgcn_mfma_f32_16x16x32_bf16(
                        a[mt], bw[nt], acc1[mt][nt], 0, 0, 0);
        }
        __syncthreads();
#pragma unroll
        for (int nt = 0; nt < 4; ++nt) {
            const int ch = nt * 16 + mh;
            const float sc = sbn1[ch], sh = sbn1[64 + ch];
#pragma unroll
            for (int mt = 0; mt < 2; ++mt)
#pragma unroll
                for (int rr = 0; rr < 4; ++rr) {
                    const float v = fmaxf(fmaf(acc1[mt][nt][rr], sc, sh), 0.0f);
                    X[(mt * 16 + q * 4 + rr) * XP + ch] = f2bf(v);
                }
        }
        __syncthreads();
        // L2 + stats accumulate + per-group (32-row) max
        const int g = blockIdx.x * 16 + c * 4 + wid;
        bf16x8 a2[2][2];
#pragma unroll
        for (int mt = 0; mt < 2; ++mt)
#pragma unroll
            for (int ks = 0; ks < 2; ++ks)
                a2[mt][ks] = *(const bf16x8*)&X[(mt * 16 + mh) * XP + ks * 32 + q * 8];
#pragma unroll
        for (int nt = 0; nt < 8; ++nt) {
            f32x4 acc[2] = {};
#pragma unroll
            for (int ks = 0; ks < 2; ++ks) {
                const bf16x8 bw = *(const bf16x8*)&sw2[(nt * 16 + mh) * WP + ks * 32 + q * 8];
#pragma unroll
                for (int mt = 0; mt < 2; ++mt)
                    acc[mt] = __builtin_amdgcn_mfma_f32_16x16x32_bf16(
                        a2[mt][ks], bw, acc[mt], 0, 0, 0);
            }
            float m = -3.0e38f;
#pragma unroll
            for (int mt = 0; mt < 2; ++mt)
#pragma unroll
                for (int rr = 0; rr < 4; ++rr) {
                    const float v = acc[mt][rr];
                    sA[nt] += v;
                    qA[nt] = fmaf(v, v, qA[nt]);
                    m = fmaxf(m, v);
                }
            m = fmaxf(m, __shfl_xor(m, 16));
            m = fmaxf(m, __shfl_xor(m, 32));
            if (q == 0) gmax[(nt * 16 + mh) * 8192 + g] = m;
        }
    }
#pragma unroll
    for (int nt = 0; nt < 8; ++nt) {
        float s = sA[nt], qq = qA[nt];
        s += __shfl_xor(s, 16); qq += __shfl_xor(qq, 16);
        s += __shfl_xor(s, 32); qq += __shfl_xor(qq, 32);
        if (q == 0) {
            red[wid][nt * 16 + mh] = s;
            red[wid][128 + nt * 16 + mh] = qq;
        }
    }
    __syncthreads();
    atomicAdd(&stats[tid],
              red[0][tid] + red[1][tid] + red[2][tid] + red[3][tid]);
}

// ---------------------------------------------------------------------------
// final: bn2 computed inline from stats2; out2[b,o,s] = relu(bn2(gmax))
// ---------------------------------------------------------------------------
__global__ __launch_bounds__(256) void final_kernel(const float* __restrict__ gmax,
                                                    const float* __restrict__ stats2,
                                                    const float* __restrict__ g2,
                                                    const float* __restrict__ be2,
                                                    float* __restrict__ out2)
{
    __shared__ float sbn[256];
    const int tid = threadIdx.x;
    if (tid < 128) {
        const float inv = 1.0f / (float)NROWS;
        const float mean = stats2[tid] * inv;
        const float var = stats2[128 + tid] * inv - mean * mean;
        const float scale = g2[tid] * rsqrtf(var + 1e-5f);
        sbn[tid] = scale;
        sbn[128 + tid] = be2[tid] - mean * scale;
    }
    __syncthreads();
    const int t = blockIdx.x * 256 + tid;
    const int s = t & 1023;
    const int o = (t >> 10) & 127;
    const int b = t >> 17;
    const int g = (b << 10) | s;
    float v = gmax[o * 8192 + g];
    v = fmaf(v, sbn[o], sbn[128 + o]);
    out2[t] = fmaxf(v, 0.0f);
}

// ---------------------------------------------------------------------------
extern "C" void kernel_launch(void* const* d_in, const int* in_sizes, int n_in,
                              void* d_out, int out_size, void* d_ws, size_t ws_size,
                              hipStream_t stream)
{
    const float* xyz = (const float*)d_in[0];
    const float* pts = (const float*)d_in[1];
    const float* w0  = (const float*)d_in[2];
    const float* g0  = (const float*)d_in[4];
    const float* be0 = (const float*)d_in[5];
    const float* w1  = (const float*)d_in[6];
    const float* g1  = (const float*)d_in[8];
    const float* be1 = (const float*)d_in[9];
    const float* w2  = (const float*)d_in[10];
    const float* g2  = (const float*)d_in[12];
    const float* be2 = (const float*)d_in[13];

    float* out_xyz = (float*)d_out;             // (B,3,1024)
    float* out2    = out_xyz + 8 * 3 * NPOINT;  // (B,128,1024)

    char* wsb = (char*)d_ws;
    int*   idxbuf  = (int*)(wsb + 32768);               // 262144 ints (1 MB)
    float* stats   = (float*)(wsb + 32768 + 1048576);   // 512 floats
    float* gmax    = stats + 1024;                      // 128*8192 floats (4 MB)
    uint4* featbuf = (uint4*)(gmax + 128 * 8192);       // 262144 uint4 (4 MB)

    float* mom    = stats;                              // 42 floats
    float* stats1 = stats + 128;
    float* stats2 = stats + 256;

    hipMemsetAsync(stats, 0, 512 * sizeof(float), stream);

    fps_kernel<<<8, 256, 0, stream>>>(xyz, out_xyz);
    ball_kernel<<<2048, 256, 0, stream>>>(xyz, pts, out_xyz, idxbuf, mom, featbuf);
    mlp1_kernel<<<512, 256, 0, stream>>>(featbuf, w0, mom, g0, be0, w1, stats1);
    mlp2_kernel<<<512, 256, 0, stream>>>(featbuf, w0, mom, g0, be0,
                                         w1, stats1, g1, be1,
                                         w2, stats2, gmax);
    final_kernel<<<4096, 256, 0, stream>>>(gmax, stats2, g2, be2, out2);
}